// Round 1
// baseline (65.162 us; speedup 1.0000x reference)
//
#include <hip/hip_runtime.h>
#include <hip/hip_bf16.h>

typedef __attribute__((ext_vector_type(8))) short short8;   // 8 bf16 (4 VGPRs) MFMA A/B frag
typedef __attribute__((ext_vector_type(4))) float fv4;      // MFMA C/D frag
typedef __attribute__((ext_vector_type(4))) int   iv4;      // 16B pack

constexpr int B_ = 16, A_ = 1024, V_ = 1024, D_ = 512;
constexpr int BM = 128, BN = 128, BK = 32;
constexpr int KT = D_ / BK;  // 16 K-steps

// fp32 -> bf16 round-to-nearest-even (bit trick)
__device__ __forceinline__ unsigned f2bf(float f) {
    unsigned u = __builtin_bit_cast(unsigned, f);
    return (u + 0x7fffu + ((u >> 16) & 1u)) >> 16;
}

__device__ __forceinline__ iv4 pack8(fv4 x, fv4 y) {
    iv4 r;
    r[0] = (int)(f2bf(x[0]) | (f2bf(x[1]) << 16));
    r[1] = (int)(f2bf(x[2]) | (f2bf(x[3]) << 16));
    r[2] = (int)(f2bf(y[0]) | (f2bf(y[1]) << 16));
    r[3] = (int)(f2bf(y[2]) | (f2bf(y[3]) << 16));
    return r;
}

// swizzled LDS byte address for (row, k-group); row stride 64B, 4x16B slots/row
__device__ __forceinline__ int slot_addr(int r, int g) {
    return r * 64 + (((g) ^ ((r >> 1) & 3)) << 4);
}

__global__ void __launch_bounds__(256)
l2dist_kernel(const float* __restrict__ audio,
              const float* __restrict__ visual,
              float* __restrict__ out)
{
    __shared__ __align__(16) char sA[BM * 64];   // 8 KB bf16 tile, swizzled
    __shared__ __align__(16) char sV[BN * 64];   // 8 KB
    __shared__ float pA[BM][4];
    __shared__ float pV[BN][4];
    __shared__ float nA[BM];
    __shared__ float nV[BN];

    const int t    = threadIdx.x;
    const int lane = t & 63;
    const int wave = t >> 6;
    const int wm   = wave >> 1;       // wave row (0..1), 64-row slab
    const int wn   = wave & 1;        // wave col (0..1), 64-col slab

    const int vb = blockIdx.x;        // V tile index
    const int ab = blockIdx.y;        // A tile index
    const int b  = blockIdx.z;        // batch

    const int r0 = t >> 2;            // staging row 0..63 (also handles r0+64)
    const int g  = t & 3;             // k-group (8 floats)

    const float* Ap = audio  + ((size_t)b * A_ + (size_t)ab * BM) * D_;
    const float* Vp = visual + ((size_t)b * V_ + (size_t)vb * BN) * D_;

    fv4 acc[4][4];
#pragma unroll
    for (int i = 0; i < 4; ++i)
#pragma unroll
        for (int j = 0; j < 4; ++j)
            acc[i][j] = fv4{0.f, 0.f, 0.f, 0.f};

    float psA0 = 0.f, psA1 = 0.f, psV0 = 0.f, psV1 = 0.f;

    const int frow = lane & 15;       // frag row/col within 16
    const int fg   = lane >> 4;       // frag k-group

    for (int kt = 0; kt < KT; ++kt) {
        const int koff = kt * BK + g * 8;
        // global loads: 8 fp32 per (row, matrix); rows r0 and r0+64
        fv4 a0 = *(const fv4*)(Ap + (size_t)r0 * D_ + koff);
        fv4 a1 = *(const fv4*)(Ap + (size_t)r0 * D_ + koff + 4);
        fv4 a2 = *(const fv4*)(Ap + (size_t)(r0 + 64) * D_ + koff);
        fv4 a3 = *(const fv4*)(Ap + (size_t)(r0 + 64) * D_ + koff + 4);
        fv4 v0 = *(const fv4*)(Vp + (size_t)r0 * D_ + koff);
        fv4 v1 = *(const fv4*)(Vp + (size_t)r0 * D_ + koff + 4);
        fv4 v2 = *(const fv4*)(Vp + (size_t)(r0 + 64) * D_ + koff);
        fv4 v3 = *(const fv4*)(Vp + (size_t)(r0 + 64) * D_ + koff + 4);

        // fp32 squared-norm partials (exact inputs, before bf16 rounding)
#pragma unroll
        for (int i = 0; i < 4; ++i) {
            psA0 += a0[i] * a0[i] + a1[i] * a1[i];
            psA1 += a2[i] * a2[i] + a3[i] * a3[i];
            psV0 += v0[i] * v0[i] + v1[i] * v1[i];
            psV1 += v2[i] * v2[i] + v3[i] * v3[i];
        }

        iv4 wa0 = pack8(a0, a1), wa1 = pack8(a2, a3);
        iv4 wv0 = pack8(v0, v1), wv1 = pack8(v2, v3);

        __syncthreads();  // prior iteration's frag reads done before overwrite
        *(iv4*)(sA + slot_addr(r0,      g)) = wa0;
        *(iv4*)(sA + slot_addr(r0 + 64, g)) = wa1;
        *(iv4*)(sV + slot_addr(r0,      g)) = wv0;
        *(iv4*)(sV + slot_addr(r0 + 64, g)) = wv1;
        __syncthreads();

        short8 af[4], bfr[4];
#pragma unroll
        for (int m = 0; m < 4; ++m)
            af[m] = *(const short8*)(sA + slot_addr(wm * 64 + m * 16 + frow, fg));
#pragma unroll
        for (int n = 0; n < 4; ++n)
            bfr[n] = *(const short8*)(sV + slot_addr(wn * 64 + n * 16 + frow, fg));

#pragma unroll
        for (int m = 0; m < 4; ++m)
#pragma unroll
            for (int n = 0; n < 4; ++n)
                acc[m][n] = __builtin_amdgcn_mfma_f32_16x16x32_bf16(
                    af[m], bfr[n], acc[m][n], 0, 0, 0);
    }

    // norm reduction: thread partials -> per-row sums
    pA[r0][g]      = psA0;
    pA[r0 + 64][g] = psA1;
    pV[r0][g]      = psV0;
    pV[r0 + 64][g] = psV1;
    __syncthreads();
    if (t < 128) {
        nA[t] = pA[t][0] + pA[t][1] + pA[t][2] + pA[t][3];
    } else {
        int r = t - 128;
        nV[r] = pV[r][0] + pV[r][1] + pV[r][2] + pV[r][3];
    }
    __syncthreads();

    // epilogue: out = sqrt(max(||a||^2 + ||v||^2 - 2*cross, 0))
    float* Ob = out + (size_t)b * A_ * V_ + ((size_t)ab * BM) * V_ + (size_t)vb * BN;
#pragma unroll
    for (int m = 0; m < 4; ++m) {
#pragma unroll
        for (int n = 0; n < 4; ++n) {
            const int col = wn * 64 + n * 16 + frow;   // C/D: col = lane&15
            const float vsq = nV[col];
#pragma unroll
            for (int j = 0; j < 4; ++j) {
                const int row = wm * 64 + m * 16 + fg * 4 + j;  // C/D: row = (lane>>4)*4+reg
                float d2 = nA[row] + vsq - 2.f * acc[m][n][j];
                d2 = fmaxf(d2, 0.f);
                Ob[(size_t)row * V_ + col] = sqrtf(d2);
            }
        }
    }
}

extern "C" void kernel_launch(void* const* d_in, const int* in_sizes, int n_in,
                              void* d_out, int out_size, void* d_ws, size_t ws_size,
                              hipStream_t stream) {
    const float* audio  = (const float*)d_in[0];
    const float* visual = (const float*)d_in[1];
    float* out = (float*)d_out;

    dim3 grid(V_ / BN, A_ / BM, B_);   // (8, 8, 16)
    dim3 block(256);
    l2dist_kernel<<<grid, block, 0, stream>>>(audio, visual, out);
}

// Round 2
// 46.333 us; speedup vs baseline: 1.4064x; 1.4064x over previous
//
#include <hip/hip_runtime.h>
#include <hip/hip_bf16.h>
#include <stdint.h>

typedef __attribute__((ext_vector_type(8))) short short8;   // 8 bf16 MFMA A/B frag
typedef __attribute__((ext_vector_type(4))) float fv4;      // MFMA C/D frag
typedef __attribute__((ext_vector_type(4))) int   iv4;      // 16B pack

constexpr int B_ = 16, A_ = 1024, V_ = 1024, D_ = 512;
constexpr int ROWS_A = B_ * A_;              // 16384
constexpr int ROWS_T = 2 * ROWS_A;           // 32768 (audio + visual rows)
constexpr size_t BF_BYTES_ONE = (size_t)ROWS_A * D_ * 2;   // 16 MiB each
constexpr size_t WS_NEED = 2 * BF_BYTES_ONE + (size_t)ROWS_T * 4;  // 32 MiB + 128 KiB

// fp32 -> bf16 round-to-nearest-even
__device__ __forceinline__ unsigned f2bf(float f) {
    unsigned u = __builtin_bit_cast(unsigned, f);
    return (u + 0x7fffu + ((u >> 16) & 1u)) >> 16;
}

// ---------------- Pass 1: fp32 -> bf16 convert + row squared-norms ----------------
__global__ void __launch_bounds__(256)
convert_kernel(const float* __restrict__ audio, const float* __restrict__ visual,
               ushort* __restrict__ abf, ushort* __restrict__ vbf,
               float* __restrict__ normA, float* __restrict__ normV)
{
    const int lane = threadIdx.x & 63;
    const int wv   = (blockIdx.x * 256 + threadIdx.x) >> 6;
    const int nw   = (gridDim.x * 256) >> 6;

    for (int row = wv; row < ROWS_T; row += nw) {
        const float* src; ushort* dst; float* nd; int r;
        if (row < ROWS_A) { src = audio;  dst = abf; nd = normA; r = row; }
        else              { src = visual; dst = vbf; nd = normV; r = row - ROWS_A; }

        const float* p = src + (size_t)r * D_ + lane * 8;   // one wave = one 512-elem row
        fv4 x0 = *(const fv4*)p;
        fv4 x1 = *(const fv4*)(p + 4);

        float s = 0.f;
#pragma unroll
        for (int i = 0; i < 4; ++i) s += x0[i] * x0[i] + x1[i] * x1[i];

        iv4 w;
        w[0] = (int)(f2bf(x0[0]) | (f2bf(x0[1]) << 16));
        w[1] = (int)(f2bf(x0[2]) | (f2bf(x0[3]) << 16));
        w[2] = (int)(f2bf(x1[0]) | (f2bf(x1[1]) << 16));
        w[3] = (int)(f2bf(x1[2]) | (f2bf(x1[3]) << 16));
        *(iv4*)(dst + (size_t)r * D_ + lane * 8) = w;

#pragma unroll
        for (int m = 1; m < 64; m <<= 1) s += __shfl_xor(s, m, 64);
        if (lane == 0) nd[r] = s;
    }
}

// ---------------- Pass 2: bf16 GEMM (m97 structure) + fused sqrt epilogue ----------------
__device__ __forceinline__ void gload16(const void* g, void* l) {
    __builtin_amdgcn_global_load_lds((const __attribute__((address_space(1))) void*)g,
                                     (__attribute__((address_space(3))) void*)l,
                                     16, 0, 0);
}

__global__ void __launch_bounds__(256, 4)
gemm_kernel(const ushort* __restrict__ abf, const ushort* __restrict__ vbf,
            const float* __restrict__ normA, const float* __restrict__ normV,
            float* __restrict__ out)
{
    // LDS tiles: [128 rows][64 bf16] linear (128 B/row), chunk-XOR handled at
    // the global SOURCE address (m173 pattern) + on the ds_read side.
    __shared__ __align__(16) char sA[128 * 128];
    __shared__ __align__(16) char sV[128 * 128];
    __shared__ float lnrm[256];

    const int t    = threadIdx.x;
    const int lane = t & 63;
    const int w    = t >> 6;
    const int wm   = w >> 1;          // wave's 64-row slab of C
    const int wn   = w & 1;           // wave's 64-col slab of C

    // XCD-bijective swizzle: 1024 blocks % 8 == 0; each XCD gets 128
    // consecutive tiles = 2 whole batches (A+V bf16 = 4 MiB = its L2).
    const int orig = blockIdx.x;
    const int wg   = (orig & 7) * 128 + (orig >> 3);
    const int b    = wg >> 6;
    const int tt   = wg & 63;
    const int ab   = tt >> 3;
    const int vb   = tt & 7;

    const ushort* Ag = abf + ((size_t)b * A_ + (size_t)ab * 128) * D_;
    const ushort* Vg = vbf + ((size_t)b * V_ + (size_t)vb * 128) * D_;

    // staging geometry: per wave-issue, 64 lanes x 16 B = 8 rows of 128 B
    const int rl = lane >> 3;                 // row within 8-row group
    const int cs = (lane & 7) ^ rl;           // swizzled source chunk (involution)

    fv4 acc[4][4];
#pragma unroll
    for (int i = 0; i < 4; ++i)
#pragma unroll
        for (int j = 0; j < 4; ++j) acc[i][j] = fv4{0.f, 0.f, 0.f, 0.f};

    const int frow = lane & 15;
    const int fg   = lane >> 4;
    const int xk   = frow & 7;                // read-side XOR key (= row & 7)

    for (int kt = 0; kt < D_ / 64; ++kt) {    // 8 K-steps of BK=64
        // ---- stage A and V tiles: 8 x global_load_lds dwordx4 per thread-wave ----
#pragma unroll
        for (int i = 0; i < 4; ++i) {
            const int row = i * 32 + w * 8 + rl;
            gload16(Ag + (size_t)row * D_ + kt * 64 + cs * 8, sA + (i * 32 + w * 8) * 128);
            gload16(Vg + (size_t)row * D_ + kt * 64 + cs * 8, sV + (i * 32 + w * 8) * 128);
        }
        __syncthreads();   // drains vmcnt: tiles ready

#pragma unroll
        for (int kk = 0; kk < 2; ++kk) {
            short8 af[4], vf[4];
#pragma unroll
            for (int m = 0; m < 4; ++m) {
                const int r = wm * 64 + m * 16 + frow;
                af[m] = *(const short8*)(sA + r * 128 + (((kk * 4 + fg) ^ xk) << 4));
            }
#pragma unroll
            for (int n = 0; n < 4; ++n) {
                const int r = wn * 64 + n * 16 + frow;
                vf[n] = *(const short8*)(sV + r * 128 + (((kk * 4 + fg) ^ xk) << 4));
            }
#pragma unroll
            for (int m = 0; m < 4; ++m)
#pragma unroll
                for (int n = 0; n < 4; ++n)
                    acc[m][n] = __builtin_amdgcn_mfma_f32_16x16x32_bf16(
                        af[m], vf[n], acc[m][n], 0, 0, 0);
        }
        __syncthreads();   // frag reads done before next overwrite
    }

    // ---- stage norms, fused epilogue ----
    if (t < 128) lnrm[t]       = normA[(size_t)b * A_ + ab * 128 + t];
    else         lnrm[t]       = normV[(size_t)b * V_ + vb * 128 + (t - 128)];
    __syncthreads();

    float* Ob = out + (size_t)b * A_ * V_ + ((size_t)ab * 128) * V_ + vb * 128;
#pragma unroll
    for (int m = 0; m < 4; ++m) {
#pragma unroll
        for (int n = 0; n < 4; ++n) {
            const int col = wn * 64 + n * 16 + frow;     // C/D: col = lane&15
            const float vsq = lnrm[128 + col];
#pragma unroll
            for (int j = 0; j < 4; ++j) {
                const int row = wm * 64 + m * 16 + fg * 4 + j;  // C/D: row = (lane>>4)*4+reg
                float d2 = lnrm[row] + vsq - 2.f * acc[m][n][j];
                Ob[(size_t)row * V_ + col] = sqrtf(fmaxf(d2, 0.f));
            }
        }
    }
}

// ---------------- Fallback: round-1 fused kernel (used only if ws too small) ----------------
__device__ __forceinline__ iv4 pack8(fv4 x, fv4 y) {
    iv4 r;
    r[0] = (int)(f2bf(x[0]) | (f2bf(x[1]) << 16));
    r[1] = (int)(f2bf(x[2]) | (f2bf(x[3]) << 16));
    r[2] = (int)(f2bf(y[0]) | (f2bf(y[1]) << 16));
    r[3] = (int)(f2bf(y[2]) | (f2bf(y[3]) << 16));
    return r;
}
__device__ __forceinline__ int slot_addr(int r, int g) {
    return r * 64 + (((g) ^ ((r >> 1) & 3)) << 4);
}

__global__ void __launch_bounds__(256)
l2dist_fused(const float* __restrict__ audio, const float* __restrict__ visual,
             float* __restrict__ out)
{
    __shared__ __align__(16) char sA[128 * 64];
    __shared__ __align__(16) char sV[128 * 64];
    __shared__ float pA[128][4];
    __shared__ float pV[128][4];
    __shared__ float nA[128];
    __shared__ float nV[128];

    const int t = threadIdx.x, lane = t & 63, wave = t >> 6;
    const int wm = wave >> 1, wn = wave & 1;
    const int vb = blockIdx.x, ab = blockIdx.y, b = blockIdx.z;
    const int r0 = t >> 2, g = t & 3;

    const float* Ap = audio  + ((size_t)b * A_ + (size_t)ab * 128) * D_;
    const float* Vp = visual + ((size_t)b * V_ + (size_t)vb * 128) * D_;

    fv4 acc[4][4];
#pragma unroll
    for (int i = 0; i < 4; ++i)
#pragma unroll
        for (int j = 0; j < 4; ++j) acc[i][j] = fv4{0.f, 0.f, 0.f, 0.f};
    float psA0 = 0.f, psA1 = 0.f, psV0 = 0.f, psV1 = 0.f;
    const int frow = lane & 15, fg = lane >> 4;

    for (int kt = 0; kt < 16; ++kt) {
        const int koff = kt * 32 + g * 8;
        fv4 a0 = *(const fv4*)(Ap + (size_t)r0 * D_ + koff);
        fv4 a1 = *(const fv4*)(Ap + (size_t)r0 * D_ + koff + 4);
        fv4 a2 = *(const fv4*)(Ap + (size_t)(r0 + 64) * D_ + koff);
        fv4 a3 = *(const fv4*)(Ap + (size_t)(r0 + 64) * D_ + koff + 4);
        fv4 v0 = *(const fv4*)(Vp + (size_t)r0 * D_ + koff);
        fv4 v1 = *(const fv4*)(Vp + (size_t)r0 * D_ + koff + 4);
        fv4 v2 = *(const fv4*)(Vp + (size_t)(r0 + 64) * D_ + koff);
        fv4 v3 = *(const fv4*)(Vp + (size_t)(r0 + 64) * D_ + koff + 4);
#pragma unroll
        for (int i = 0; i < 4; ++i) {
            psA0 += a0[i] * a0[i] + a1[i] * a1[i];
            psA1 += a2[i] * a2[i] + a3[i] * a3[i];
            psV0 += v0[i] * v0[i] + v1[i] * v1[i];
            psV1 += v2[i] * v2[i] + v3[i] * v3[i];
        }
        iv4 wa0 = pack8(a0, a1), wa1 = pack8(a2, a3);
        iv4 wv0 = pack8(v0, v1), wv1 = pack8(v2, v3);
        __syncthreads();
        *(iv4*)(sA + slot_addr(r0, g)) = wa0;
        *(iv4*)(sA + slot_addr(r0 + 64, g)) = wa1;
        *(iv4*)(sV + slot_addr(r0, g)) = wv0;
        *(iv4*)(sV + slot_addr(r0 + 64, g)) = wv1;
        __syncthreads();
        short8 af[4], bfr[4];
#pragma unroll
        for (int m = 0; m < 4; ++m)
            af[m] = *(const short8*)(sA + slot_addr(wm * 64 + m * 16 + frow, fg));
#pragma unroll
        for (int n = 0; n < 4; ++n)
            bfr[n] = *(const short8*)(sV + slot_addr(wn * 64 + n * 16 + frow, fg));
#pragma unroll
        for (int m = 0; m < 4; ++m)
#pragma unroll
            for (int n = 0; n < 4; ++n)
                acc[m][n] = __builtin_amdgcn_mfma_f32_16x16x32_bf16(af[m], bfr[n], acc[m][n], 0, 0, 0);
    }

    pA[r0][g] = psA0; pA[r0 + 64][g] = psA1;
    pV[r0][g] = psV0; pV[r0 + 64][g] = psV1;
    __syncthreads();
    if (t < 128) nA[t] = pA[t][0] + pA[t][1] + pA[t][2] + pA[t][3];
    else { int r = t - 128; nV[r] = pV[r][0] + pV[r][1] + pV[r][2] + pV[r][3]; }
    __syncthreads();

    float* Ob = out + (size_t)b * A_ * V_ + ((size_t)ab * 128) * V_ + vb * 128;
#pragma unroll
    for (int m = 0; m < 4; ++m)
#pragma unroll
        for (int n = 0; n < 4; ++n) {
            const int col = wn * 64 + n * 16 + frow;
            const float vsq = nV[col];
#pragma unroll
            for (int j = 0; j < 4; ++j) {
                const int row = wm * 64 + m * 16 + fg * 4 + j;
                float d2 = nA[row] + vsq - 2.f * acc[m][n][j];
                Ob[(size_t)row * V_ + col] = sqrtf(fmaxf(d2, 0.f));
            }
        }
}

extern "C" void kernel_launch(void* const* d_in, const int* in_sizes, int n_in,
                              void* d_out, int out_size, void* d_ws, size_t ws_size,
                              hipStream_t stream) {
    const float* audio  = (const float*)d_in[0];
    const float* visual = (const float*)d_in[1];
    float* out = (float*)d_out;

    if (ws_size >= WS_NEED) {
        char* ws = (char*)d_ws;
        ushort* abf = (ushort*)ws;
        ushort* vbf = (ushort*)(ws + BF_BYTES_ONE);
        float*  nA  = (float*)(ws + 2 * BF_BYTES_ONE);
        float*  nV  = nA + ROWS_A;
        convert_kernel<<<2048, 256, 0, stream>>>(audio, visual, abf, vbf, nA, nV);
        gemm_kernel<<<1024, 256, 0, stream>>>(abf, vbf, nA, nV, out);
    } else {
        dim3 grid(8, 8, 16);
        l2dist_fused<<<grid, 256, 0, stream>>>(audio, visual, out);
    }
}